// Round 3
// baseline (773.521 us; speedup 1.0000x reference)
//
#include <hip/hip_runtime.h>
#include <hip/hip_bf16.h>
#include <cstdint>
#include <cstddef>

// Problem constants
#define BB   512
#define NN   100
#define HH   768
#define II   1536
#define MM   (BB*NN)          // 51200 rows
#define APAD 776              // 768 + 8 bf16 pad -> LDS stride 388 dwords

typedef __bf16 bf16;
typedef __bf16 bf16x4 __attribute__((ext_vector_type(4)));
typedef __bf16 bf16x8 __attribute__((ext_vector_type(8)));
typedef float  f32x4  __attribute__((ext_vector_type(4)));

// ---------------------------------------------------------------------------
// prep: W1 fp32 [768][1536] -> Wp bf16 [1536][768] (n-major, k-contiguous),
//       gw[i] = gamma[i]*W2[i] (fp32), scal = {S1 = sum gamma*W2,
//       S2 = sum beta*W2 + b2}   (all inputs fp32 per reference)
// ---------------------------------------------------------------------------
__global__ __launch_bounds__(256) void prep_kernel(
    const float* __restrict__ W1, const float* __restrict__ gamma,
    const float* __restrict__ beta, const float* __restrict__ W2,
    const float* __restrict__ b2,
    bf16* __restrict__ Wp, float* __restrict__ gw, float* __restrict__ scal)
{
    int bid = blockIdx.x;
    if (bid < 1152) {
        // 1152*256 = 294912 threads = 1536 n * 192 k-quads
        int t  = bid * 256 + threadIdx.x;
        int n  = t % II;
        int k0 = (t / II) * 4;               // 0..764
        bf16x4 v;
        v[0] = (bf16)W1[(size_t)(k0+0)*II + n];   // coalesced reads (n fastest)
        v[1] = (bf16)W1[(size_t)(k0+1)*II + n];
        v[2] = (bf16)W1[(size_t)(k0+2)*II + n];
        v[3] = (bf16)W1[(size_t)(k0+3)*II + n];
        *(bf16x4*)&Wp[(size_t)n*HH + k0] = v;
    } else if (bid == 1152) {
        for (int j = threadIdx.x; j < II; j += 256)
            gw[j] = gamma[j] * W2[j];
    } else {
        float s1 = 0.f, s2 = 0.f;
        for (int j = threadIdx.x; j < II; j += 256) {
            float w2 = W2[j];
            s1 += gamma[j] * w2;
            s2 += beta[j]  * w2;
        }
        #pragma unroll
        for (int off = 32; off; off >>= 1) {
            s1 += __shfl_down(s1, off, 64);
            s2 += __shfl_down(s2, off, 64);
        }
        __shared__ float a1[4], a2[4];
        int lane = threadIdx.x & 63, w = threadIdx.x >> 6;
        if (lane == 0) { a1[w] = s1; a2[w] = s2; }
        __syncthreads();
        if (threadIdx.x == 0) {
            scal[0] = a1[0] + a1[1] + a1[2] + a1[3];
            scal[1] = a2[0] + a2[1] + a2[2] + a2[3] + b2[0];
        }
    }
}

// ---------------------------------------------------------------------------
// Fully fused: h = gelu(A @ W1 + b1); LN(h); score = sigmoid(h_ln . W2 + b2)
// h never materialized. Block = 1024 threads (16 waves) owns 32 rows x all
// 1536 cols. A (fp32) is staged once into LDS as bf16 (row stride 776 ->
// conflict-free ds_read_b128). Wave w owns a 96-col slice: 2 row-tiles x
// 6 col-tiles of 16x16x32 bf16 MFMA. B fragments read直接 from Wp (bf16,
// 2.36 MB, L2-resident). LN folded: z = rstd*(sum h*gw - mu*S1) + S2.
// ---------------------------------------------------------------------------
__global__ __launch_bounds__(1024) void fused_mlp(
    const float* __restrict__ A, const bf16* __restrict__ Wp,
    const float* __restrict__ b1, const float* __restrict__ gw,
    const float* __restrict__ scal, float* __restrict__ scores)
{
    __shared__ bf16  As[32 * APAD];      // 49.7 KB
    __shared__ float sred[16][32][3];    // 6 KB

    const int tid  = threadIdx.x;
    const int w    = tid >> 6;           // 0..15
    const int lane = tid & 63;
    const int m15  = lane & 15;
    const int q    = lane >> 4;          // 0..3
    const int row0 = blockIdx.x * 32;
    const int colbase = w * 96;

    // ---- stage A tile (32 rows x 768 cols fp32 -> bf16 LDS) ----
    #pragma unroll
    for (int i = 0; i < 6; ++i) {
        const int linear = i * 1024 + tid;       // 0..6143
        const int row = linear / 192;            // 768/4 = 192 float4 per row
        const int c4  = linear % 192;
        float4 v = *(const float4*)&A[(size_t)(row0 + row) * HH + c4 * 4];
        bf16x4 o = { (bf16)v.x, (bf16)v.y, (bf16)v.z, (bf16)v.w };
        *(bf16x4*)&As[row * APAD + c4 * 4] = o;
    }
    __syncthreads();

    // ---- MFMA main loop ----
    const bf16* bb = Wp + (size_t)(colbase + m15) * HH;
    f32x4 acc[2][6] = {};

    for (int kb = 0; kb < 24; ++kb) {
        const int koff = kb * 32 + q * 8;
        bf16x8 af0 = *(const bf16x8*)&As[(     m15) * APAD + koff];
        bf16x8 af1 = *(const bf16x8*)&As[(16 + m15) * APAD + koff];
        bf16x8 bfr[6];
        #pragma unroll
        for (int ct = 0; ct < 6; ++ct)
            bfr[ct] = *(const bf16x8*)(bb + (size_t)ct * 16 * HH + koff);
        #pragma unroll
        for (int ct = 0; ct < 6; ++ct) {
            acc[0][ct] = __builtin_amdgcn_mfma_f32_16x16x32_bf16(
                af0, bfr[ct], acc[0][ct], 0, 0, 0);
            acc[1][ct] = __builtin_amdgcn_mfma_f32_16x16x32_bf16(
                af1, bfr[ct], acc[1][ct], 0, 0, 0);
        }
    }

    // ---- epilogue: +b1, exact GELU, partial LN stats over own 6 cols ----
    float bv[6], gv[6];
    #pragma unroll
    for (int ct = 0; ct < 6; ++ct) {
        const int col = colbase + ct * 16 + m15;
        bv[ct] = b1[col];
        gv[ct] = gw[col];
    }

    float sh[2][4] = {}, shh[2][4] = {}, shg[2][4] = {};
    #pragma unroll
    for (int mt = 0; mt < 2; ++mt)
        #pragma unroll
        for (int ct = 0; ct < 6; ++ct)
            #pragma unroll
            for (int r = 0; r < 4; ++r) {
                // C/D layout: col = lane&15, row = q*4 + r
                float x = acc[mt][ct][r] + bv[ct];
                float g = 0.5f * x * (1.0f + erff(x * 0.70710678118654752f));
                sh[mt][r]  += g;
                shh[mt][r] += g * g;
                shg[mt][r] += g * gv[ct];
            }

    // reduce across the 16 lanes (m15) holding the same row
    #pragma unroll
    for (int mt = 0; mt < 2; ++mt)
        #pragma unroll
        for (int r = 0; r < 4; ++r) {
            float x0 = sh[mt][r], x1 = shh[mt][r], x2 = shg[mt][r];
            #pragma unroll
            for (int off = 8; off; off >>= 1) {
                x0 += __shfl_down(x0, off, 16);
                x1 += __shfl_down(x1, off, 16);
                x2 += __shfl_down(x2, off, 16);
            }
            if (m15 == 0) {
                const int rl = mt * 16 + q * 4 + r;   // 0..31, each once
                sred[w][rl][0] = x0;
                sred[w][rl][1] = x1;
                sred[w][rl][2] = x2;
            }
        }
    __syncthreads();

    // combine 16 wave-partials, finish LN + sigmoid
    if (tid < 32) {
        float Sh = 0.f, Shh = 0.f, Shg = 0.f;
        #pragma unroll
        for (int i = 0; i < 16; ++i) {
            Sh  += sred[i][tid][0];
            Shh += sred[i][tid][1];
            Shg += sred[i][tid][2];
        }
        const float mu   = Sh * (1.0f / II);
        const float var  = Shh * (1.0f / II) - mu * mu;
        const float rstd = rsqrtf(var + 1e-5f);
        const float z    = rstd * (Shg - mu * scal[0]) + scal[1];
        scores[row0 + tid] = 1.0f / (1.0f + __expf(-z));
    }
}

// ---------------------------------------------------------------------------
// pred = sum over N of scores; logits = one_hot(clamp(round(pred),0,15))
// ---------------------------------------------------------------------------
__global__ __launch_bounds__(128) void pred_logits(
    const float* __restrict__ scores, float* __restrict__ out_pred,
    float* __restrict__ out_logits)
{
    const int b = blockIdx.x, t = threadIdx.x;
    float v = (t < NN) ? scores[b * NN + t] : 0.0f;
    #pragma unroll
    for (int off = 32; off; off >>= 1) v += __shfl_down(v, off, 64);
    __shared__ float ssum[2];
    const int lane = t & 63, w = t >> 6;
    if (lane == 0) ssum[w] = v;
    __syncthreads();
    const float p = ssum[0] + ssum[1];
    if (t == 0) out_pred[b] = p;
    if (t < 16) {
        int aid = (int)rintf(p);
        aid = aid < 0 ? 0 : (aid > 15 ? 15 : aid);
        out_logits[b * 16 + t] = (t == aid) ? 1.0f : 0.0f;
    }
}

// ---------------------------------------------------------------------------
extern "C" void kernel_launch(void* const* d_in, const int* in_sizes, int n_in,
                              void* d_out, int out_size, void* d_ws, size_t ws_size,
                              hipStream_t stream)
{
    const float* v_emb = (const float*)d_in[0];
    const float* W1    = (const float*)d_in[1];
    const float* b1    = (const float*)d_in[2];
    const float* gamma = (const float*)d_in[3];
    const float* beta  = (const float*)d_in[4];
    const float* W2    = (const float*)d_in[5];
    const float* b2    = (const float*)d_in[6];

    // workspace: 2.4 MB
    char* ws = (char*)d_ws;
    size_t off = 0;
    bf16*  Wp   = (bf16*)(ws + off);  off += (size_t)II * HH * 2;   // 2,359,296
    float* gw   = (float*)(ws + off); off += (size_t)II * 4;        // 6,144
    float* scal = (float*)(ws + off); off += 256;

    float* out       = (float*)d_out;
    float* o_scores  = out;            // [B*N] = 51200
    float* o_pred    = out + MM;       // 512
    float* o_logits  = out + MM + BB;  // 8192

    hipLaunchKernelGGL(prep_kernel, dim3(1154), dim3(256), 0, stream,
                       W1, gamma, beta, W2, b2, Wp, gw, scal);
    hipLaunchKernelGGL(fused_mlp, dim3(MM / 32), dim3(1024), 0, stream,
                       v_emb, Wp, b1, gw, scal, o_scores);
    hipLaunchKernelGGL(pred_logits, dim3(BB), dim3(128), 0, stream,
                       o_scores, o_pred, o_logits);
}

// Round 4
// 455.289 us; speedup vs baseline: 1.6990x; 1.6990x over previous
//
#include <hip/hip_runtime.h>
#include <hip/hip_bf16.h>
#include <cstdint>
#include <cstddef>

// Problem constants
#define BB   512
#define NN   100
#define HH   768
#define II   1536
#define MM   (BB*NN)          // 51200 rows

typedef __bf16 bf16;
typedef __bf16 bf16x4 __attribute__((ext_vector_type(4)));
typedef __bf16 bf16x8 __attribute__((ext_vector_type(8)));
typedef float  f32x4  __attribute__((ext_vector_type(4)));

// async global -> LDS, 16B per lane (wave-uniform LDS base + lane*16)
__device__ __forceinline__ void gld_lds16(const bf16* g, bf16* l) {
    __builtin_amdgcn_global_load_lds(
        (const __attribute__((address_space(1))) void*)g,
        (__attribute__((address_space(3))) void*)l, 16, 0, 0);
}

// ---------------------------------------------------------------------------
// prep: W1 fp32 [768][1536] -> Wp bf16 [1536][768]; gw = gamma*W2 (fp32);
//       scal = {S1 = sum gamma*W2, S2 = sum beta*W2 + b2}
// ---------------------------------------------------------------------------
__global__ __launch_bounds__(256) void prep_kernel(
    const float* __restrict__ W1, const float* __restrict__ gamma,
    const float* __restrict__ beta, const float* __restrict__ W2,
    const float* __restrict__ b2,
    bf16* __restrict__ Wp, float* __restrict__ gw, float* __restrict__ scal)
{
    int bid = blockIdx.x;
    if (bid < 1152) {
        int t  = bid * 256 + threadIdx.x;
        int n  = t % II;
        int k0 = (t / II) * 4;
        bf16x4 v;
        v[0] = (bf16)W1[(size_t)(k0+0)*II + n];
        v[1] = (bf16)W1[(size_t)(k0+1)*II + n];
        v[2] = (bf16)W1[(size_t)(k0+2)*II + n];
        v[3] = (bf16)W1[(size_t)(k0+3)*II + n];
        *(bf16x4*)&Wp[(size_t)n*HH + k0] = v;
    } else if (bid == 1152) {
        for (int j = threadIdx.x; j < II; j += 256)
            gw[j] = gamma[j] * W2[j];
    } else {
        float s1 = 0.f, s2 = 0.f;
        for (int j = threadIdx.x; j < II; j += 256) {
            float w2 = W2[j];
            s1 += gamma[j] * w2;
            s2 += beta[j]  * w2;
        }
        #pragma unroll
        for (int off = 32; off; off >>= 1) {
            s1 += __shfl_down(s1, off, 64);
            s2 += __shfl_down(s2, off, 64);
        }
        __shared__ float a1[4], a2[4];
        int lane = threadIdx.x & 63, w = threadIdx.x >> 6;
        if (lane == 0) { a1[w] = s1; a2[w] = s2; }
        __syncthreads();
        if (threadIdx.x == 0) {
            scal[0] = a1[0] + a1[1] + a1[2] + a1[3];
            scal[1] = a2[0] + a2[1] + a2[2] + a2[3] + b2[0];
        }
    }
}

// ---------------------------------------------------------------------------
// conv: v_emb fp32 -> bf16 Apk [51200][768] (only used when ws is big enough)
// ---------------------------------------------------------------------------
__global__ __launch_bounds__(256) void conv_kernel(
    const float* __restrict__ A, bf16* __restrict__ Apk)
{
    const size_t i = ((size_t)blockIdx.x * 256 + threadIdx.x) * 4;
    float4 v = *(const float4*)&A[i];
    bf16x4 o = { (bf16)v.x, (bf16)v.y, (bf16)v.z, (bf16)v.w };
    *(bf16x4*)&Apk[i] = o;
}

// ---------------------------------------------------------------------------
// gemm_part: 128x128 tile, BK=64, 16x16x32 bf16 MFMA (m97 recipe).
// Epilogue: +b1, exact GELU, per-row partial LN stats over this block's
// 128 cols -> part[row][3][12]  (s-major then col-block nb).
// LDS: As/Bs [128 rows][8 slots of 8 elems]; slot g holds k-group g^(row&7)
// so global_load_lds (lane*16 dest) works AND ds_read_b128 is conflict-light.
// PK=true: A already bf16 (Apk, staged via global_load_lds).
// PK=false: A fp32, staged with manual load+cvt+ds_write_b128.
// ---------------------------------------------------------------------------
template <bool PK>
__global__ __launch_bounds__(256) void gemm_part(
    const float* __restrict__ Af, const bf16* __restrict__ Apk,
    const bf16* __restrict__ Wp, const float* __restrict__ b1,
    const float* __restrict__ gw, float* __restrict__ part)
{
    __shared__ bf16  As[128 * 64];      // 16 KB
    __shared__ bf16  Bs[128 * 64];      // 16 KB
    __shared__ float sred[2][128][3];   // 3 KB

    const int tid  = threadIdx.x;
    const int nb   = blockIdx.x % 12;
    const int mb   = blockIdx.x / 12;
    const int lane = tid & 63;
    const int w    = tid >> 6;
    const int wm   = w >> 1;            // 0..1
    const int wn   = w & 1;             // 0..1
    const int m15  = lane & 15;
    const int q    = lane >> 4;         // 0..3
    const int row0 = mb * 128;

    // staging indices: per it-chunk thread covers row rsub=tid>>3, slot tid&7
    const int rsub = tid >> 3;                    // 0..31
    const int kgA  = (tid & 7) ^ (rsub & 7);      // k-group stored in my slot
    const size_t gbase = (size_t)rsub * HH + (size_t)kgA * 8;
    const int    lbase = tid * 8;                 // LDS element offset

    const bf16* Bg = Wp + (size_t)(nb * 128) * HH;

    f32x4 acc[4][4] = {};

    for (int kt = 0; kt < 12; ++kt) {
        const int koff = kt * 64;
        if (PK) {
            const bf16* Ag = Apk + (size_t)row0 * HH;
            #pragma unroll
            for (int it = 0; it < 4; ++it) {
                size_t go = gbase + (size_t)it * 32 * HH + koff;
                int    lo = lbase + it * 2048;
                gld_lds16(Ag + go, &As[lo]);
                gld_lds16(Bg + go, &Bs[lo]);
            }
        } else {
            #pragma unroll
            for (int it = 0; it < 4; ++it) {
                size_t go = gbase + (size_t)it * 32 * HH + koff;
                gld_lds16(Bg + go, &Bs[lbase + it * 2048]);
            }
            #pragma unroll
            for (int it = 0; it < 4; ++it) {
                const float* src = Af + (size_t)(row0 + it*32 + rsub) * HH
                                      + koff + kgA * 8;
                float4 v0 = *(const float4*)(src);
                float4 v1 = *(const float4*)(src + 4);
                bf16x8 o = { (bf16)v0.x, (bf16)v0.y, (bf16)v0.z, (bf16)v0.w,
                             (bf16)v1.x, (bf16)v1.y, (bf16)v1.z, (bf16)v1.w };
                *(bf16x8*)&As[lbase + it * 2048] = o;
            }
        }
        asm volatile("s_waitcnt vmcnt(0)" ::: "memory");
        __syncthreads();

        #pragma unroll
        for (int kb = 0; kb < 2; ++kb) {
            const int swz = (((kb * 4 + q) ^ (m15 & 7)) * 8);
            bf16x8 af[4], bfr[4];
            #pragma unroll
            for (int mt = 0; mt < 4; ++mt)
                af[mt] = *(const bf16x8*)&As[(wm*64 + mt*16 + m15) * 64 + swz];
            #pragma unroll
            for (int nt = 0; nt < 4; ++nt)
                bfr[nt] = *(const bf16x8*)&Bs[(wn*64 + nt*16 + m15) * 64 + swz];
            #pragma unroll
            for (int mt = 0; mt < 4; ++mt)
                #pragma unroll
                for (int nt = 0; nt < 4; ++nt)
                    acc[mt][nt] = __builtin_amdgcn_mfma_f32_16x16x32_bf16(
                        af[mt], bfr[nt], acc[mt][nt], 0, 0, 0);
        }
        __syncthreads();
    }

    // epilogue: +b1, exact GELU, per-row partial stats over this block's cols
    float bv[4], gv[4];
    #pragma unroll
    for (int nt = 0; nt < 4; ++nt) {
        const int col = nb*128 + wn*64 + nt*16 + m15;
        bv[nt] = b1[col];
        gv[nt] = gw[col];
    }

    #pragma unroll
    for (int mt = 0; mt < 4; ++mt) {
        #pragma unroll
        for (int r = 0; r < 4; ++r) {
            float x0 = 0.f, x1 = 0.f, x2 = 0.f;
            #pragma unroll
            for (int nt = 0; nt < 4; ++nt) {
                // C/D layout: col = lane&15, row = q*4 + r
                float x = acc[mt][nt][r] + bv[nt];
                float g = 0.5f * x * (1.0f + erff(x * 0.70710678118654752f));
                x0 += g; x1 += g * g; x2 += g * gv[nt];
            }
            #pragma unroll
            for (int off = 8; off; off >>= 1) {
                x0 += __shfl_down(x0, off, 16);
                x1 += __shfl_down(x1, off, 16);
                x2 += __shfl_down(x2, off, 16);
            }
            if (m15 == 0) {
                const int rl = wm*64 + mt*16 + q*4 + r;   // 0..127
                sred[wn][rl][0] = x0;
                sred[wn][rl][1] = x1;
                sred[wn][rl][2] = x2;
            }
        }
    }
    __syncthreads();

    if (tid < 128) {
        const size_t rg = (size_t)(row0 + tid);
        #pragma unroll
        for (int s = 0; s < 3; ++s)
            part[rg * 36 + s * 12 + nb] = sred[0][tid][s] + sred[1][tid][s];
    }
}

// ---------------------------------------------------------------------------
// ln_finish: reduce 12 col-block partials per row, finish LN + sigmoid
// ---------------------------------------------------------------------------
__global__ __launch_bounds__(256) void ln_finish(
    const float* __restrict__ part, const float* __restrict__ scal,
    float* __restrict__ scores)
{
    const size_t row = (size_t)blockIdx.x * 256 + threadIdx.x;
    const float* p = part + row * 36;
    float Sh = 0.f, Shh = 0.f, Shg = 0.f;
    #pragma unroll
    for (int j = 0; j < 12; ++j) {
        Sh  += p[j];
        Shh += p[12 + j];
        Shg += p[24 + j];
    }
    const float mu   = Sh * (1.0f / II);
    const float var  = Shh * (1.0f / II) - mu * mu;
    const float rstd = rsqrtf(var + 1e-5f);
    const float z    = rstd * (Shg - mu * scal[0]) + scal[1];
    scores[row] = 1.0f / (1.0f + __expf(-z));
}

// ---------------------------------------------------------------------------
// pred = sum over N of scores; logits = one_hot(clamp(round(pred),0,15))
// ---------------------------------------------------------------------------
__global__ __launch_bounds__(128) void pred_logits(
    const float* __restrict__ scores, float* __restrict__ out_pred,
    float* __restrict__ out_logits)
{
    const int b = blockIdx.x, t = threadIdx.x;
    float v = (t < NN) ? scores[b * NN + t] : 0.0f;
    #pragma unroll
    for (int off = 32; off; off >>= 1) v += __shfl_down(v, off, 64);
    __shared__ float ssum[2];
    const int lane = t & 63, w = t >> 6;
    if (lane == 0) ssum[w] = v;
    __syncthreads();
    const float p = ssum[0] + ssum[1];
    if (t == 0) out_pred[b] = p;
    if (t < 16) {
        int aid = (int)rintf(p);
        aid = aid < 0 ? 0 : (aid > 15 ? 15 : aid);
        out_logits[b * 16 + t] = (t == aid) ? 1.0f : 0.0f;
    }
}

// ---------------------------------------------------------------------------
extern "C" void kernel_launch(void* const* d_in, const int* in_sizes, int n_in,
                              void* d_out, int out_size, void* d_ws, size_t ws_size,
                              hipStream_t stream)
{
    const float* v_emb = (const float*)d_in[0];
    const float* W1    = (const float*)d_in[1];
    const float* b1    = (const float*)d_in[2];
    const float* gamma = (const float*)d_in[3];
    const float* beta  = (const float*)d_in[4];
    const float* W2    = (const float*)d_in[5];
    const float* b2    = (const float*)d_in[6];

    char* ws = (char*)d_ws;
    size_t off = 0;
    bf16*  Wp   = (bf16*)(ws + off);  off += (size_t)II * HH * 2;      // 2,359,296
    float* gw   = (float*)(ws + off); off += (size_t)II * 4;           // 6,144
    float* scal = (float*)(ws + off); off += 256;
    float* part = (float*)(ws + off); off += (size_t)MM * 36 * 4;      // 7,372,800
    bf16*  Apk  = (bf16*)(ws + off);
    const size_t need_pk = off + (size_t)MM * HH * 2;                  // ~88.4 MB
    const bool   use_pk  = (ws_size >= need_pk);

    float* out       = (float*)d_out;
    float* o_scores  = out;            // 51200
    float* o_pred    = out + MM;       // 512
    float* o_logits  = out + MM + BB;  // 8192

    hipLaunchKernelGGL(prep_kernel, dim3(1154), dim3(256), 0, stream,
                       W1, gamma, beta, W2, b2, Wp, gw, scal);
    if (use_pk) {
        hipLaunchKernelGGL(conv_kernel, dim3((MM * HH) / (256 * 4)), dim3(256),
                           0, stream, v_emb, Apk);
        hipLaunchKernelGGL((gemm_part<true>), dim3((MM / 128) * 12), dim3(256),
                           0, stream, v_emb, Apk, Wp, b1, gw, part);
    } else {
        hipLaunchKernelGGL((gemm_part<false>), dim3((MM / 128) * 12), dim3(256),
                           0, stream, v_emb, Apk, Wp, b1, gw, part);
    }
    hipLaunchKernelGGL(ln_finish, dim3(MM / 256), dim3(256), 0, stream,
                       part, scal, o_scores);
    hipLaunchKernelGGL(pred_logits, dim3(BB), dim3(128), 0, stream,
                       o_scores, o_pred, o_logits);
}

// Round 5
// 428.982 us; speedup vs baseline: 1.8032x; 1.0613x over previous
//
#include <hip/hip_runtime.h>
#include <hip/hip_bf16.h>
#include <cstdint>
#include <cstddef>

// Problem constants
#define BB   512
#define NN   100
#define HH   768
#define II   1536
#define MM   (BB*NN)          // 51200 rows

typedef __bf16 bf16;
typedef __bf16 bf16x4 __attribute__((ext_vector_type(4)));
typedef __bf16 bf16x8 __attribute__((ext_vector_type(8)));
typedef float  f32x4  __attribute__((ext_vector_type(4)));

// async global -> LDS, 16B per lane (wave-uniform LDS base + lane*16)
__device__ __forceinline__ void gld_lds16(const bf16* g, bf16* l) {
    __builtin_amdgcn_global_load_lds(
        (const __attribute__((address_space(1))) void*)g,
        (__attribute__((address_space(3))) void*)l, 16, 0, 0);
}

// Fast exact-GELU: erf via Abramowitz-Stegun 7.1.26 (|err| <= 1.5e-7)
// ~14 VALU insts vs ~30 for ocml erff.
__device__ __forceinline__ float fast_gelu(float x) {
    const float ax = fabsf(x) * 0.70710678118654752f;   // |x|/sqrt(2)
    const float t  = __builtin_amdgcn_rcpf(fmaf(0.3275911f, ax, 1.0f));
    float p = fmaf(1.061405429f, t, -1.453152027f);
    p = fmaf(p, t, 1.421413741f);
    p = fmaf(p, t, -0.284496736f);
    p = fmaf(p, t, 0.254829592f);
    p = p * t;
    const float e    = __expf(-ax * ax);
    const float erfa = fmaf(-p, e, 1.0f);               // erf(|x|/sqrt2)
    const float erfx = copysignf(erfa, x);
    return 0.5f * x * (1.0f + erfx);
}

// ---------------------------------------------------------------------------
// prep: W1 fp32 [768][1536] -> Wp bf16 [1536][768]; gw = gamma*W2 (fp32);
//       scal = {S1 = sum gamma*W2, S2 = sum beta*W2 + b2}
// ---------------------------------------------------------------------------
__global__ __launch_bounds__(256) void prep_kernel(
    const float* __restrict__ W1, const float* __restrict__ gamma,
    const float* __restrict__ beta, const float* __restrict__ W2,
    const float* __restrict__ b2,
    bf16* __restrict__ Wp, float* __restrict__ gw, float* __restrict__ scal)
{
    int bid = blockIdx.x;
    if (bid < 1152) {
        int t  = bid * 256 + threadIdx.x;
        int n  = t % II;
        int k0 = (t / II) * 4;
        bf16x4 v;
        v[0] = (bf16)W1[(size_t)(k0+0)*II + n];
        v[1] = (bf16)W1[(size_t)(k0+1)*II + n];
        v[2] = (bf16)W1[(size_t)(k0+2)*II + n];
        v[3] = (bf16)W1[(size_t)(k0+3)*II + n];
        *(bf16x4*)&Wp[(size_t)n*HH + k0] = v;
    } else if (bid == 1152) {
        for (int j = threadIdx.x; j < II; j += 256)
            gw[j] = gamma[j] * W2[j];
    } else {
        float s1 = 0.f, s2 = 0.f;
        for (int j = threadIdx.x; j < II; j += 256) {
            float w2 = W2[j];
            s1 += gamma[j] * w2;
            s2 += beta[j]  * w2;
        }
        #pragma unroll
        for (int off = 32; off; off >>= 1) {
            s1 += __shfl_down(s1, off, 64);
            s2 += __shfl_down(s2, off, 64);
        }
        __shared__ float a1[4], a2[4];
        int lane = threadIdx.x & 63, w = threadIdx.x >> 6;
        if (lane == 0) { a1[w] = s1; a2[w] = s2; }
        __syncthreads();
        if (threadIdx.x == 0) {
            scal[0] = a1[0] + a1[1] + a1[2] + a1[3];
            scal[1] = a2[0] + a2[1] + a2[2] + a2[3] + b2[0];
        }
    }
}

// ---------------------------------------------------------------------------
// conv: v_emb fp32 -> bf16 Apk [51200][768]
// ---------------------------------------------------------------------------
__global__ __launch_bounds__(256) void conv_kernel(
    const float* __restrict__ A, bf16* __restrict__ Apk)
{
    const size_t i = ((size_t)blockIdx.x * 256 + threadIdx.x) * 4;
    float4 v = *(const float4*)&A[i];
    bf16x4 o = { (bf16)v.x, (bf16)v.y, (bf16)v.z, (bf16)v.w };
    *(bf16x4*)&Apk[i] = o;
}

// ---------------------------------------------------------------------------
// gemm_part: 128x128 tile, BK=64, 16x16x32 bf16 MFMA (m97 recipe).
// XCD-aware swizzle: the 12 col-blocks sharing an A-tile run consecutively
// on ONE XCD (A-tile fetched into that XCD's L2 once, reused 12x).
// Epilogue: +b1, fast exact GELU, per-row partial LN stats over the block's
// 128 cols -> part[s][nb][row] (contiguous 512B runs per block -> no write
// amplification).
// ---------------------------------------------------------------------------
__global__ __launch_bounds__(256) void gemm_part(
    const bf16* __restrict__ Apk, const bf16* __restrict__ Wp,
    const float* __restrict__ b1, const float* __restrict__ gw,
    float* __restrict__ part)
{
    __shared__ bf16  As[128 * 64];      // 16 KB
    __shared__ bf16  Bs[128 * 64];      // 16 KB
    __shared__ float sred[2][128][3];   // 3 KB

    const int tid  = threadIdx.x;
    // XCD swizzle: 4800 blocks = 8 XCDs x 600; 600 = 50 mb x 12 nb
    const int lin  = (blockIdx.x % 8) * 600 + blockIdx.x / 8;
    const int mb   = lin / 12;
    const int nb   = lin % 12;
    const int lane = tid & 63;
    const int w    = tid >> 6;
    const int wm   = w >> 1;            // 0..1
    const int wn   = w & 1;             // 0..1
    const int m15  = lane & 15;
    const int q    = lane >> 4;         // 0..3
    const int row0 = mb * 128;

    // staging: thread covers row rsub=tid>>3, slot tid&7; slot g holds
    // k-group g^(rsub&7) so lane*16 LDS dest works AND ds_read is clean
    const int rsub = tid >> 3;                    // 0..31
    const int kgA  = (tid & 7) ^ (rsub & 7);
    const size_t gbase = (size_t)rsub * HH + (size_t)kgA * 8;
    const int    lbase = tid * 8;

    const bf16* Ag = Apk + (size_t)row0 * HH;
    const bf16* Bg = Wp  + (size_t)(nb * 128) * HH;

    f32x4 acc[4][4] = {};

    for (int kt = 0; kt < 12; ++kt) {
        const int koff = kt * 64;
        #pragma unroll
        for (int it = 0; it < 4; ++it) {
            size_t go = gbase + (size_t)it * 32 * HH + koff;
            int    lo = lbase + it * 2048;
            gld_lds16(Ag + go, &As[lo]);
            gld_lds16(Bg + go, &Bs[lo]);
        }
        asm volatile("s_waitcnt vmcnt(0)" ::: "memory");
        __syncthreads();

        #pragma unroll
        for (int kb = 0; kb < 2; ++kb) {
            const int swz = (((kb * 4 + q) ^ (m15 & 7)) * 8);
            bf16x8 af[4], bfr[4];
            #pragma unroll
            for (int mt = 0; mt < 4; ++mt)
                af[mt] = *(const bf16x8*)&As[(wm*64 + mt*16 + m15) * 64 + swz];
            #pragma unroll
            for (int nt = 0; nt < 4; ++nt)
                bfr[nt] = *(const bf16x8*)&Bs[(wn*64 + nt*16 + m15) * 64 + swz];
            #pragma unroll
            for (int mt = 0; mt < 4; ++mt)
                #pragma unroll
                for (int nt = 0; nt < 4; ++nt)
                    acc[mt][nt] = __builtin_amdgcn_mfma_f32_16x16x32_bf16(
                        af[mt], bfr[nt], acc[mt][nt], 0, 0, 0);
        }
        __syncthreads();
    }

    // epilogue: +b1, fast GELU, per-row partial stats over this block's cols
    float bv[4], gv[4];
    #pragma unroll
    for (int nt = 0; nt < 4; ++nt) {
        const int col = nb*128 + wn*64 + nt*16 + m15;
        bv[nt] = b1[col];
        gv[nt] = gw[col];
    }

    #pragma unroll
    for (int mt = 0; mt < 4; ++mt) {
        #pragma unroll
        for (int r = 0; r < 4; ++r) {
            float x0 = 0.f, x1 = 0.f, x2 = 0.f;
            #pragma unroll
            for (int nt = 0; nt < 4; ++nt) {
                // C/D layout: col = lane&15, row = q*4 + r
                float g = fast_gelu(acc[mt][nt][r] + bv[nt]);
                x0 += g; x1 += g * g; x2 += g * gv[nt];
            }
            #pragma unroll
            for (int off = 8; off; off >>= 1) {
                x0 += __shfl_down(x0, off, 16);
                x1 += __shfl_down(x1, off, 16);
                x2 += __shfl_down(x2, off, 16);
            }
            if (m15 == 0) {
                const int rl = wm*64 + mt*16 + q*4 + r;   // 0..127
                sred[wn][rl][0] = x0;
                sred[wn][rl][1] = x1;
                sred[wn][rl][2] = x2;
            }
        }
    }
    __syncthreads();

    if (tid < 128) {
        const size_t rg = (size_t)row0 + tid;
        #pragma unroll
        for (int s = 0; s < 3; ++s)
            part[(size_t)s * 12 * MM + (size_t)nb * MM + rg]
                = sred[0][tid][s] + sred[1][tid][s];
    }
}

// ---------------------------------------------------------------------------
// score_pred: finish LN + sigmoid for the 100 rows of batch b, write scores,
// then pred = sum(scores), logits = one_hot(clamp(round(pred),0,15))
// ---------------------------------------------------------------------------
__global__ __launch_bounds__(128) void score_pred(
    const float* __restrict__ part, const float* __restrict__ scal,
    float* __restrict__ o_scores, float* __restrict__ o_pred,
    float* __restrict__ o_logits)
{
    const int b = blockIdx.x, t = threadIdx.x;
    float s = 0.f;
    if (t < NN) {
        const size_t row = (size_t)b * NN + t;
        float Sh = 0.f, Shh = 0.f, Shg = 0.f;
        #pragma unroll
        for (int j = 0; j < 12; ++j) {
            Sh  += part[(size_t)0*12*MM + (size_t)j*MM + row];
            Shh += part[(size_t)1*12*MM + (size_t)j*MM + row];
            Shg += part[(size_t)2*12*MM + (size_t)j*MM + row];
        }
        const float mu   = Sh * (1.0f / II);
        const float var  = Shh * (1.0f / II) - mu * mu;
        const float rstd = rsqrtf(var + 1e-5f);
        const float z    = rstd * (Shg - mu * scal[0]) + scal[1];
        s = 1.0f / (1.0f + __expf(-z));
        o_scores[row] = s;
    }
    float v = s;
    #pragma unroll
    for (int off = 32; off; off >>= 1) v += __shfl_down(v, off, 64);
    __shared__ float ssum[2];
    const int lane = t & 63, w = t >> 6;
    if (lane == 0) ssum[w] = v;
    __syncthreads();
    const float p = ssum[0] + ssum[1];
    if (t == 0) o_pred[b] = p;
    if (t < 16) {
        int aid = (int)rintf(p);
        aid = aid < 0 ? 0 : (aid > 15 ? 15 : aid);
        o_logits[b * 16 + t] = (t == aid) ? 1.0f : 0.0f;
    }
}

// ---------------------------------------------------------------------------
extern "C" void kernel_launch(void* const* d_in, const int* in_sizes, int n_in,
                              void* d_out, int out_size, void* d_ws, size_t ws_size,
                              hipStream_t stream)
{
    const float* v_emb = (const float*)d_in[0];
    const float* W1    = (const float*)d_in[1];
    const float* b1    = (const float*)d_in[2];
    const float* gamma = (const float*)d_in[3];
    const float* beta  = (const float*)d_in[4];
    const float* W2    = (const float*)d_in[5];
    const float* b2    = (const float*)d_in[6];

    char* ws = (char*)d_ws;
    size_t off = 0;
    bf16*  Wp   = (bf16*)(ws + off);  off += (size_t)II * HH * 2;      // 2.36 MB
    float* gw   = (float*)(ws + off); off += (size_t)II * 4;
    float* scal = (float*)(ws + off); off += 256;
    float* part = (float*)(ws + off); off += (size_t)MM * 36 * 4;      // 7.37 MB
    bf16*  Apk  = (bf16*)(ws + off);                                   // 78.6 MB

    float* out       = (float*)d_out;
    float* o_scores  = out;            // 51200
    float* o_pred    = out + MM;       // 512
    float* o_logits  = out + MM + BB;  // 8192

    hipLaunchKernelGGL(prep_kernel, dim3(1154), dim3(256), 0, stream,
                       W1, gamma, beta, W2, b2, Wp, gw, scal);
    hipLaunchKernelGGL(conv_kernel, dim3((MM * HH) / (256 * 4)), dim3(256),
                       0, stream, v_emb, Apk);
    hipLaunchKernelGGL(gemm_part, dim3((MM / 128) * 12), dim3(256),
                       0, stream, Apk, Wp, b1, gw, part);
    hipLaunchKernelGGL(score_pred, dim3(BB), dim3(128), 0, stream,
                       part, scal, o_scores, o_pred, o_logits);
}

// Round 6
// 393.978 us; speedup vs baseline: 1.9634x; 1.0888x over previous
//
#include <hip/hip_runtime.h>
#include <hip/hip_bf16.h>
#include <cstdint>
#include <cstddef>

// Problem constants
#define BB   512
#define NN   100
#define HH   768
#define II   1536
#define MM   (BB*NN)          // 51200 rows

typedef __bf16 bf16;
typedef __bf16 bf16x4 __attribute__((ext_vector_type(4)));
typedef __bf16 bf16x8 __attribute__((ext_vector_type(8)));
typedef float  f32x4  __attribute__((ext_vector_type(4)));

// async global -> LDS, 16B per lane (wave-uniform LDS base + lane*16)
__device__ __forceinline__ void gld_lds16(const bf16* g, bf16* l) {
    __builtin_amdgcn_global_load_lds(
        (const __attribute__((address_space(1))) void*)g,
        (__attribute__((address_space(3))) void*)l, 16, 0, 0);
}

// butterfly add over 16-lane groups via ds_swizzle (BitMode, single DS inst)
template <int PAT>
__device__ __forceinline__ float swz_add(float x) {
    return x + __int_as_float(
        __builtin_amdgcn_ds_swizzle(__float_as_int(x), PAT));
}
__device__ __forceinline__ float red16(float x) {
    x = swz_add<0x041F>(x);   // xor 1
    x = swz_add<0x081F>(x);   // xor 2
    x = swz_add<0x101F>(x);   // xor 4
    x = swz_add<0x201F>(x);   // xor 8
    return x;                 // all 16 lanes hold the group sum
}

// Fast exact-GELU: erf via Abramowitz-Stegun 7.1.26 (|err| <= 1.5e-7)
__device__ __forceinline__ float fast_gelu(float x) {
    const float ax = fabsf(x) * 0.70710678118654752f;   // |x|/sqrt(2)
    const float t  = __builtin_amdgcn_rcpf(fmaf(0.3275911f, ax, 1.0f));
    float p = fmaf(1.061405429f, t, -1.453152027f);
    p = fmaf(p, t, 1.421413741f);
    p = fmaf(p, t, -0.284496736f);
    p = fmaf(p, t, 0.254829592f);
    p = p * t;
    const float e    = __expf(-ax * ax);
    const float erfa = fmaf(-p, e, 1.0f);               // erf(|x|/sqrt2)
    const float erfx = copysignf(erfa, x);
    return 0.5f * x * (1.0f + erfx);
}

// ---------------------------------------------------------------------------
// prep: W1 fp32 [768][1536] -> Wp bf16 [1536][768]; gw = gamma*W2 (fp32);
//       scal = {S1 = sum gamma*W2, S2 = sum beta*W2 + b2}
// ---------------------------------------------------------------------------
__global__ __launch_bounds__(256) void prep_kernel(
    const float* __restrict__ W1, const float* __restrict__ gamma,
    const float* __restrict__ beta, const float* __restrict__ W2,
    const float* __restrict__ b2,
    bf16* __restrict__ Wp, float* __restrict__ gw, float* __restrict__ scal)
{
    int bid = blockIdx.x;
    if (bid < 1152) {
        int t  = bid * 256 + threadIdx.x;
        int n  = t % II;
        int k0 = (t / II) * 4;
        bf16x4 v;
        v[0] = (bf16)W1[(size_t)(k0+0)*II + n];
        v[1] = (bf16)W1[(size_t)(k0+1)*II + n];
        v[2] = (bf16)W1[(size_t)(k0+2)*II + n];
        v[3] = (bf16)W1[(size_t)(k0+3)*II + n];
        *(bf16x4*)&Wp[(size_t)n*HH + k0] = v;
    } else if (bid == 1152) {
        for (int j = threadIdx.x; j < II; j += 256)
            gw[j] = gamma[j] * W2[j];
    } else {
        float s1 = 0.f, s2 = 0.f;
        for (int j = threadIdx.x; j < II; j += 256) {
            float w2 = W2[j];
            s1 += gamma[j] * w2;
            s2 += beta[j]  * w2;
        }
        #pragma unroll
        for (int off = 32; off; off >>= 1) {
            s1 += __shfl_down(s1, off, 64);
            s2 += __shfl_down(s2, off, 64);
        }
        __shared__ float a1[4], a2[4];
        int lane = threadIdx.x & 63, w = threadIdx.x >> 6;
        if (lane == 0) { a1[w] = s1; a2[w] = s2; }
        __syncthreads();
        if (threadIdx.x == 0) {
            scal[0] = a1[0] + a1[1] + a1[2] + a1[3];
            scal[1] = a2[0] + a2[1] + a2[2] + a2[3] + b2[0];
        }
    }
}

// ---------------------------------------------------------------------------
// gemm_part: 128x128 tile, BK=64, 16x16x32 bf16 MFMA.
// A read DIRECTLY from fp32 v_emb (float4-pair load + cvt + ds_write_b128,
// no separate conversion pass); B staged via async global_load_lds.
// XCD-aware swizzle: 12 col-blocks sharing an A-tile run on one XCD.
// Epilogue: +b1, fast GELU, per-row partial LN stats -> part[s][nb][row].
// ---------------------------------------------------------------------------
__global__ __launch_bounds__(256) void gemm_part(
    const float* __restrict__ Af, const bf16* __restrict__ Wp,
    const float* __restrict__ b1, const float* __restrict__ gw,
    float* __restrict__ part)
{
    __shared__ bf16  As[128 * 64];      // 16 KB
    __shared__ bf16  Bs[128 * 64];      // 16 KB
    __shared__ float sred[2][128][3];   // 3 KB

    const int tid  = threadIdx.x;
    // XCD swizzle: 4800 blocks = 8 XCDs x 600; 600 = 50 mb x 12 nb
    const int lin  = (blockIdx.x % 8) * 600 + blockIdx.x / 8;
    const int mb   = lin / 12;
    const int nb   = lin % 12;
    const int lane = tid & 63;
    const int w    = tid >> 6;
    const int wm   = w >> 1;            // 0..1
    const int wn   = w & 1;             // 0..1
    const int m15  = lane & 15;
    const int q    = lane >> 4;         // 0..3
    const int row0 = mb * 128;

    // staging: thread covers row rsub=tid>>3, slot tid&7; slot g holds
    // k-group g^(rsub&7) so lane*16 LDS dest works AND ds_read is clean
    const int rsub = tid >> 3;                    // 0..31
    const int kg   = (tid & 7) ^ (rsub & 7);
    const int lbase = tid * 8;

    const float* aP = Af + (size_t)(row0    + rsub) * HH + kg * 8;
    const bf16*  bP = Wp + (size_t)(nb*128 + rsub) * HH + kg * 8;

    f32x4 acc[4][4] = {};

    for (int kt = 0; kt < 12; ++kt) {
        #pragma unroll
        for (int it = 0; it < 4; ++it)
            gld_lds16(bP + (size_t)it * 32 * HH, &Bs[lbase + it * 2048]);
        #pragma unroll
        for (int it = 0; it < 4; ++it) {
            const float* s = aP + (size_t)it * 32 * HH;
            float4 v0 = *(const float4*)(s);
            float4 v1 = *(const float4*)(s + 4);
            bf16x8 o = { (bf16)v0.x, (bf16)v0.y, (bf16)v0.z, (bf16)v0.w,
                         (bf16)v1.x, (bf16)v1.y, (bf16)v1.z, (bf16)v1.w };
            *(bf16x8*)&As[lbase + it * 2048] = o;
        }
        asm volatile("s_waitcnt vmcnt(0)" ::: "memory");
        __syncthreads();

        #pragma unroll
        for (int kb = 0; kb < 2; ++kb) {
            const int swz = (((kb * 4 + q) ^ (m15 & 7)) * 8);
            bf16x8 af[4], bfr[4];
            #pragma unroll
            for (int mt = 0; mt < 4; ++mt)
                af[mt] = *(const bf16x8*)&As[(wm*64 + mt*16 + m15) * 64 + swz];
            #pragma unroll
            for (int nt = 0; nt < 4; ++nt)
                bfr[nt] = *(const bf16x8*)&Bs[(wn*64 + nt*16 + m15) * 64 + swz];
            #pragma unroll
            for (int mt = 0; mt < 4; ++mt)
                #pragma unroll
                for (int nt = 0; nt < 4; ++nt)
                    acc[mt][nt] = __builtin_amdgcn_mfma_f32_16x16x32_bf16(
                        af[mt], bfr[nt], acc[mt][nt], 0, 0, 0);
        }
        __syncthreads();
        aP += 64; bP += 64;
    }

    // epilogue: +b1, fast GELU, per-row partial stats over this block's cols
    float bv[4], gv[4];
    #pragma unroll
    for (int nt = 0; nt < 4; ++nt) {
        const int col = nb*128 + wn*64 + nt*16 + m15;
        bv[nt] = b1[col];
        gv[nt] = gw[col];
    }

    #pragma unroll
    for (int mt = 0; mt < 4; ++mt) {
        #pragma unroll
        for (int r = 0; r < 4; ++r) {
            float x0 = 0.f, x1 = 0.f, x2 = 0.f;
            #pragma unroll
            for (int nt = 0; nt < 4; ++nt) {
                // C/D layout: col = lane&15, row = q*4 + r
                float g = fast_gelu(acc[mt][nt][r] + bv[nt]);
                x0 += g; x1 += g * g; x2 += g * gv[nt];
            }
            x0 = red16(x0); x1 = red16(x1); x2 = red16(x2);
            if (m15 == 0) {
                const int rl = wm*64 + mt*16 + q*4 + r;   // 0..127
                sred[wn][rl][0] = x0;
                sred[wn][rl][1] = x1;
                sred[wn][rl][2] = x2;
            }
        }
    }
    __syncthreads();

    if (tid < 128) {
        const size_t rg = (size_t)row0 + tid;
        #pragma unroll
        for (int s = 0; s < 3; ++s)
            part[(size_t)s * 12 * MM + (size_t)nb * MM + rg]
                = sred[0][tid][s] + sred[1][tid][s];
    }
}

// ---------------------------------------------------------------------------
// score_pred: finish LN + sigmoid for the 100 rows of batch b, write scores,
// then pred = sum(scores), logits = one_hot(clamp(round(pred),0,15))
// ---------------------------------------------------------------------------
__global__ __launch_bounds__(128) void score_pred(
    const float* __restrict__ part, const float* __restrict__ scal,
    float* __restrict__ o_scores, float* __restrict__ o_pred,
    float* __restrict__ o_logits)
{
    const int b = blockIdx.x, t = threadIdx.x;
    float s = 0.f;
    if (t < NN) {
        const size_t row = (size_t)b * NN + t;
        float Sh = 0.f, Shh = 0.f, Shg = 0.f;
        #pragma unroll
        for (int j = 0; j < 12; ++j) {
            Sh  += part[(size_t)0*12*MM + (size_t)j*MM + row];
            Shh += part[(size_t)1*12*MM + (size_t)j*MM + row];
            Shg += part[(size_t)2*12*MM + (size_t)j*MM + row];
        }
        const float mu   = Sh * (1.0f / II);
        const float var  = Shh * (1.0f / II) - mu * mu;
        const float rstd = rsqrtf(var + 1e-5f);
        const float z    = rstd * (Shg - mu * scal[0]) + scal[1];
        s = 1.0f / (1.0f + __expf(-z));
        o_scores[row] = s;
    }
    float v = s;
    #pragma unroll
    for (int off = 32; off; off >>= 1) v += __shfl_down(v, off, 64);
    __shared__ float ssum[2];
    const int lane = t & 63, w = t >> 6;
    if (lane == 0) ssum[w] = v;
    __syncthreads();
    const float p = ssum[0] + ssum[1];
    if (t == 0) o_pred[b] = p;
    if (t < 16) {
        int aid = (int)rintf(p);
        aid = aid < 0 ? 0 : (aid > 15 ? 15 : aid);
        o_logits[b * 16 + t] = (t == aid) ? 1.0f : 0.0f;
    }
}

// ---------------------------------------------------------------------------
extern "C" void kernel_launch(void* const* d_in, const int* in_sizes, int n_in,
                              void* d_out, int out_size, void* d_ws, size_t ws_size,
                              hipStream_t stream)
{
    const float* v_emb = (const float*)d_in[0];
    const float* W1    = (const float*)d_in[1];
    const float* b1    = (const float*)d_in[2];
    const float* gamma = (const float*)d_in[3];
    const float* beta  = (const float*)d_in[4];
    const float* W2    = (const float*)d_in[5];
    const float* b2    = (const float*)d_in[6];

    char* ws = (char*)d_ws;
    size_t off = 0;
    bf16*  Wp   = (bf16*)(ws + off);  off += (size_t)II * HH * 2;      // 2.36 MB
    float* gw   = (float*)(ws + off); off += (size_t)II * 4;
    float* scal = (float*)(ws + off); off += 256;
    float* part = (float*)(ws + off); off += (size_t)MM * 36 * 4;      // 7.37 MB

    float* out       = (float*)d_out;
    float* o_scores  = out;            // 51200
    float* o_pred    = out + MM;       // 512
    float* o_logits  = out + MM + BB;  // 8192

    hipLaunchKernelGGL(prep_kernel, dim3(1154), dim3(256), 0, stream,
                       W1, gamma, beta, W2, b2, Wp, gw, scal);
    hipLaunchKernelGGL(gemm_part, dim3((MM / 128) * 12), dim3(256),
                       0, stream, v_emb, Wp, b1, gw, part);
    hipLaunchKernelGGL(score_pred, dim3(BB), dim3(128), 0, stream,
                       part, scal, o_scores, o_pred, o_logits);
}